// Round 4
// baseline (273.061 us; speedup 1.0000x reference)
//
#include <hip/hip_runtime.h>
#include <hip/hip_bf16.h>
#include <hip/hip_fp16.h>
#include <stdint.h>

// Problem constants (from reference)
#define DIM   512
#define NH    8
#define HD    64
#define NB    16
#define NTOK  1024
#define KHOPS 5

typedef __attribute__((ext_vector_type(8))) short bf16x8;   // 8 bf16 = 4 VGPR
typedef __attribute__((ext_vector_type(4))) float f32x4;

#define LOG2E 1.4426950408889634f

__device__ __forceinline__ unsigned short f32_to_bf16(float f) {
    unsigned int u = __builtin_bit_cast(unsigned int, f);
    unsigned int r = (u + 0x7FFFu + ((u >> 16) & 1u)) >> 16;   // RNE
    return (unsigned short)r;
}

__device__ __forceinline__ float fast_exp2(float x) {
    return __builtin_amdgcn_exp2f(x);
}

#define AS1C(p) ((const __attribute__((address_space(1))) void*)(p))
#define AS3(p)  ((__attribute__((address_space(3))) void*)(p))

// ---------------------------------------------------------------------------
// fp32 -> bf16 convert (vectorized)
// ---------------------------------------------------------------------------
__global__ __launch_bounds__(256) void cvt_f32_bf16(const float* __restrict__ in,
                                                    unsigned short* __restrict__ out, int n4) {
    int i = blockIdx.x * 256 + threadIdx.x;
    if (i < n4) {
        float4 v = reinterpret_cast<const float4*>(in)[i];
        ushort4 o;
        o.x = f32_to_bf16(v.x); o.y = f32_to_bf16(v.y);
        o.z = f32_to_bf16(v.z); o.w = f32_to_bf16(v.w);
        reinterpret_cast<ushort4*>(out)[i] = o;
    }
}

// ---------------------------------------------------------------------------
// Fused hop-bias: biasT fp16 [h][i/32][j][i%32]
//   = rel_alpha[h]*LOG2E * sum_k softmax(hop_logits[h])[k] * H[k][i][j]
// One block per (jt, it, h): read H tiles coalesced, combine in registers,
// transpose through an fp16 LDS tile, write coalesced.
// ---------------------------------------------------------------------------
__global__ __launch_bounds__(256) void bias_fused(const float* __restrict__ H,
                                                  const float* __restrict__ hop_logits,
                                                  const float* __restrict__ rel_alpha,
                                                  uint32_t* __restrict__ biast) {
    __shared__ unsigned short Ls[64 * 76];   // stride 76: 8B-aligned rows, 2-way-max banks
    const int tid = threadIdx.x;
    const int jt = blockIdx.x, it = blockIdx.y, h = blockIdx.z;
    const int j0 = jt * 64, i0 = it * 64;
    // per-thread softmax coefficients (tiny, redundant per thread)
    float cf[KHOPS];
    {
        float m = -1e30f;
#pragma unroll
        for (int k = 0; k < KHOPS; ++k) m = fmaxf(m, hop_logits[h * KHOPS + k]);
        float s = 0.f;
#pragma unroll
        for (int k = 0; k < KHOPS; ++k) { cf[k] = fast_exp2((hop_logits[h * KHOPS + k] - m) * LOG2E); s += cf[k]; }
        float ra = rel_alpha[h] * LOG2E / s;
#pragma unroll
        for (int k = 0; k < KHOPS; ++k) cf[k] *= ra;
    }
    const int r = tid >> 2, c0 = (tid & 3) * 16;
    float acc[16];
#pragma unroll
    for (int e = 0; e < 16; ++e) acc[e] = 0.f;
    for (int k = 0; k < KHOPS; ++k) {
        const float4* src = reinterpret_cast<const float4*>(
            H + (size_t)k * 1048576 + (size_t)(i0 + r) * 1024 + j0 + c0);
#pragma unroll
        for (int q = 0; q < 4; ++q) {
            float4 v = src[q];
            acc[q * 4 + 0] += cf[k] * v.x; acc[q * 4 + 1] += cf[k] * v.y;
            acc[q * 4 + 2] += cf[k] * v.z; acc[q * 4 + 3] += cf[k] * v.w;
        }
    }
#pragma unroll
    for (int q = 0; q < 4; ++q) {
        __half2 p0 = __floats2half2_rn(acc[q * 4 + 0], acc[q * 4 + 1]);
        __half2 p1 = __floats2half2_rn(acc[q * 4 + 2], acc[q * 4 + 3]);
        uint32_t* d = reinterpret_cast<uint32_t*>(&Ls[r * 76 + c0 + q * 4]);
        d[0] = __builtin_bit_cast(uint32_t, p0);
        d[1] = __builtin_bit_cast(uint32_t, p1);
    }
    __syncthreads();
    const int iw2 = tid & 15, jl = tid >> 4;
#pragma unroll
    for (int g = 0; g < 2; ++g)
#pragma unroll
        for (int t = 0; t < 4; ++t) {
            int j = t * 16 + jl;
            int i = g * 32 + iw2 * 2;
            uint32_t lo = (uint32_t)Ls[i * 76 + j] | ((uint32_t)Ls[(i + 1) * 76 + j] << 16);
            biast[(size_t)((h * 32 + (i0 >> 5) + g) * 1024 + (j0 + j)) * 16 + iw2] = lo;
        }
}

// ---------------------------------------------------------------------------
// GEMM  C[M,Nn] = A[M,K] * Bw[Nn,K]^T   (both bf16 row-major along K; m97-style)
// ---------------------------------------------------------------------------
template <bool BF16_OUT>
__global__ __launch_bounds__(256) void gemm_bt(const unsigned short* __restrict__ A,
                                               const unsigned short* __restrict__ Bw,
                                               void* __restrict__ Cout,
                                               const float* __restrict__ cbias,  // only fp32 path
                                               int M, int Nn, int K) {
    __shared__ unsigned short As[128 * 32];
    __shared__ unsigned short Bs[128 * 32];
    const int tid  = threadIdx.x;
    const int lane = tid & 63;
    const int w    = tid >> 6;
    const int wr   = (w >> 1) * 64, wc = (w & 1) * 64;
    const int l15  = lane & 15, quad = lane >> 4;
    const int m0   = blockIdx.x * 128, n0 = blockIdx.y * 128;

    f32x4 acc[4][4];
#pragma unroll
    for (int i = 0; i < 4; ++i)
#pragma unroll
        for (int j = 0; j < 4; ++j) { acc[i][j][0] = 0.f; acc[i][j][1] = 0.f; acc[i][j][2] = 0.f; acc[i][j][3] = 0.f; }

    for (int k0 = 0; k0 < K; k0 += 32) {
        __syncthreads();
#pragma unroll
        for (int t = 0; t < 2; ++t) {
            int c = t * 256 + w * 64 + lane;
            int r = c >> 2, kh = c & 3;
            const unsigned short* ga = A  + (size_t)(m0 + r) * K + k0 + kh * 8;
            const unsigned short* gb = Bw + (size_t)(n0 + r) * K + k0 + kh * 8;
            __builtin_amdgcn_global_load_lds(AS1C(ga), AS3(&As[(t * 256 + w * 64) * 8]), 16, 0, 0);
            __builtin_amdgcn_global_load_lds(AS1C(gb), AS3(&Bs[(t * 256 + w * 64) * 8]), 16, 0, 0);
        }
        __syncthreads();
        bf16x8 af[4], bfr[4];
#pragma unroll
        for (int rt = 0; rt < 4; ++rt)
            af[rt] = *reinterpret_cast<const bf16x8*>(&As[(wr + rt * 16 + l15) * 32 + quad * 8]);
#pragma unroll
        for (int ct = 0; ct < 4; ++ct)
            bfr[ct] = *reinterpret_cast<const bf16x8*>(&Bs[(wc + ct * 16 + l15) * 32 + quad * 8]);
#pragma unroll
        for (int rt = 0; rt < 4; ++rt)
#pragma unroll
            for (int ct = 0; ct < 4; ++ct)
                acc[rt][ct] = __builtin_amdgcn_mfma_f32_16x16x32_bf16(af[rt], bfr[ct], acc[rt][ct], 0, 0, 0);
    }

    if (BF16_OUT) {
        unsigned short* C = (unsigned short*)Cout;
#pragma unroll
        for (int rt = 0; rt < 4; ++rt)
#pragma unroll
            for (int ct = 0; ct < 4; ++ct)
#pragma unroll
                for (int reg = 0; reg < 4; ++reg) {
                    int row = m0 + wr + rt * 16 + quad * 4 + reg;
                    int col = n0 + wc + ct * 16 + l15;
                    C[(size_t)row * Nn + col] = f32_to_bf16(acc[rt][ct][reg]);
                }
    } else {
        float* C = (float*)Cout;
#pragma unroll
        for (int ct = 0; ct < 4; ++ct) {
            int col = n0 + wc + ct * 16 + l15;
            float bv = cbias[col];
#pragma unroll
            for (int rt = 0; rt < 4; ++rt)
#pragma unroll
                for (int reg = 0; reg < 4; ++reg) {
                    int row = m0 + wr + rt * 16 + quad * 4 + reg;
                    C[(size_t)row * Nn + col] = acc[rt][ct][reg] + bv;
                }
        }
    }
}

// ---------------------------------------------------------------------------
// V transpose: qkv V-columns [B,N,(v)H,64] -> vt [B,H,64,N]
// ---------------------------------------------------------------------------
__global__ __launch_bounds__(256) void transpose_v(const unsigned short* __restrict__ qkv,
                                                   unsigned short* __restrict__ vt) {
    __shared__ unsigned short Ts[64 * 66];
    const int tid = threadIdx.x;
    const int jt = blockIdx.x, h = blockIdx.y, b = blockIdx.z;
    const int j0 = jt * 64;
#pragma unroll
    for (int t = 0; t < 2; ++t) {
        int c = t * 256 + tid;
        int j = c >> 3, dh = c & 7;
        const uint32_t* g = reinterpret_cast<const uint32_t*>(
            qkv + (size_t)(b * 1024 + j0 + j) * 1536 + 1024 + h * 64 + dh * 8);
        uint32_t d0 = g[0], d1 = g[1], d2 = g[2], d3 = g[3];
        uint32_t* ls = reinterpret_cast<uint32_t*>(&Ts[j * 66 + dh * 8]);
        ls[0] = d0; ls[1] = d1; ls[2] = d2; ls[3] = d3;
    }
    __syncthreads();
#pragma unroll
    for (int t = 0; t < 2; ++t) {
        int c = t * 256 + tid;
        int d = c >> 3, jh = c & 7;
        unsigned short tmp[8];
#pragma unroll
        for (int e = 0; e < 8; ++e) tmp[e] = Ts[(jh * 8 + e) * 66 + d];
        uint32_t o0 = (uint32_t)tmp[0] | ((uint32_t)tmp[1] << 16);
        uint32_t o1 = (uint32_t)tmp[2] | ((uint32_t)tmp[3] << 16);
        uint32_t o2 = (uint32_t)tmp[4] | ((uint32_t)tmp[5] << 16);
        uint32_t o3 = (uint32_t)tmp[6] | ((uint32_t)tmp[7] << 16);
        uint32_t* gout = reinterpret_cast<uint32_t*>(
            vt + ((size_t)((b * 8 + h) * 64 + d)) * 1024 + j0 + jh * 8);
        gout[0] = o0; gout[1] = o1; gout[2] = o2; gout[3] = o3;
    }
}

// ---------------------------------------------------------------------------
// Flash attention v4: Q-tile 256 (4 waves x 64 rows), double-buffered K/V LDS
// staging (global_load_lds w16, XOR chunk swizzle), ONE barrier per j-tile:
// prefetch for tile j+1 issued right after the barrier so the compiler's
// vmcnt(0) drain at the NEXT barrier lands a full compute phase after issue.
// No-max softmax (scores bounded), row sums via ones-MFMA.
// ---------------------------------------------------------------------------
__global__ __launch_bounds__(256, 2) void flash_attn(const unsigned short* __restrict__ qkv,
                                                     const unsigned short* __restrict__ vt,
                                                     const unsigned short* __restrict__ biast,
                                                     unsigned short* __restrict__ aout) {
    __shared__ unsigned short Kb[2][64 * 64];
    __shared__ unsigned short Vb[2][64 * 64];
    __shared__ unsigned short Ps[4][64 * 72];
    const int tid  = threadIdx.x;
    const int lane = tid & 63, w = tid >> 6;
    const int l15  = lane & 15, quad = lane >> 4, l7 = l15 & 7;
    const int qt = blockIdx.x, h = blockIdx.y, b = blockIdx.z;
    const int i0 = qt * 256 + w * 64;            // this wave's first query row
    const float kscale = 0.125f * LOG2E;         // SCALE * log2(e)

    // Q fragments: A[m=lane&15][k=quad*8+j]  (direct global; read once)
    bf16x8 qf[4][2];
#pragma unroll
    for (int rt = 0; rt < 4; ++rt)
#pragma unroll
        for (int ks = 0; ks < 2; ++ks)
            qf[rt][ks] = *reinterpret_cast<const bf16x8*>(
                qkv + (size_t)(b * 1024 + i0 + rt * 16 + l15) * 1536 + h * 64 + ks * 32 + quad * 8);

    f32x4 o[4][4];
    f32x4 lacc[4];
#pragma unroll
    for (int rt = 0; rt < 4; ++rt) {
#pragma unroll
        for (int nt = 0; nt < 4; ++nt) { o[rt][nt][0] = 0.f; o[rt][nt][1] = 0.f; o[rt][nt][2] = 0.f; o[rt][nt][3] = 0.f; }
        lacc[rt][0] = 0.f; lacc[rt][1] = 0.f; lacc[rt][2] = 0.f; lacc[rt][3] = 0.f;
    }

    bf16x8 ones;
#pragma unroll
    for (int e = 0; e < 8; ++e) ones[e] = (short)0x3F80;   // bf16 1.0

    // staging: lane -> local row rl = w*16 + t*8 + srow, global chunk gch = (lane&7)^srow
    const int srow = lane >> 3;
    const int gch  = (lane & 7) ^ srow;
    const unsigned short* kgbase = qkv + (size_t)b * 1024 * 1536 + 512 + h * 64 + gch * 8;
    const unsigned short* vgbase = vt + (size_t)((b * 8 + h) * 64) * 1024 + gch * 8;
    // bias: biasT[h][i32][j][i%32]; this wave's i32 base = qt*8 + w*2
    const unsigned short* bb = biast + (size_t)(h * 32 + qt * 8 + w * 2) * 32768 + quad * 4;
    unsigned short* ps = &Ps[w][0];

    // prologue: stage tile 0 into buf 0; load bias for tile 0
    uint2 bl[2][4][4];
#pragma unroll
    for (int t = 0; t < 2; ++t) {
        int rl = w * 16 + t * 8 + srow;
        __builtin_amdgcn_global_load_lds(AS1C(kgbase + (size_t)rl * 1536),
                                         AS3(&Kb[0][(w * 16 + t * 8) * 64]), 16, 0, 0);
        __builtin_amdgcn_global_load_lds(AS1C(vgbase + (size_t)rl * 1024),
                                         AS3(&Vb[0][(w * 16 + t * 8) * 64]), 16, 0, 0);
    }
#pragma unroll
    for (int rt = 0; rt < 4; ++rt)
#pragma unroll
        for (int jt = 0; jt < 4; ++jt)
            bl[0][rt][jt] = *reinterpret_cast<const uint2*>(
                bb + (rt >> 1) * 32768 + (size_t)(jt * 16 + l15) * 32 + (rt & 1) * 16);

#pragma unroll 2
    for (int it = 0; it < 16; ++it) {
        const int cur = it & 1, nxt = cur ^ 1;
        const int j0 = it * 64;
        __syncthreads();   // drains this wave's prefetch (issued a full tile ago); frees buf[nxt]

        // prefetch next tile (fire-and-forget) + next bias (registers)
        if (it < 15) {
            const int j0n = j0 + 64;
#pragma unroll
            for (int t = 0; t < 2; ++t) {
                int rl = w * 16 + t * 8 + srow;
                __builtin_amdgcn_global_load_lds(AS1C(kgbase + (size_t)(j0n + rl) * 1536),
                                                 AS3(&Kb[nxt][(w * 16 + t * 8) * 64]), 16, 0, 0);
                __builtin_amdgcn_global_load_lds(AS1C(vgbase + (size_t)rl * 1024 + j0n),
                                                 AS3(&Vb[nxt][(w * 16 + t * 8) * 64]), 16, 0, 0);
            }
#pragma unroll
            for (int rt = 0; rt < 4; ++rt)
#pragma unroll
                for (int jt = 0; jt < 4; ++jt)
                    bl[nxt][rt][jt] = *reinterpret_cast<const uint2*>(
                        bb + (rt >> 1) * 32768 + (size_t)(j0n + jt * 16 + l15) * 32 + (rt & 1) * 16);
        }

        // QK^T + exp, in rt-pair halves (bounds s-liveness to 32 VGPRs)
#pragma unroll
        for (int rth = 0; rth < 2; ++rth) {
            f32x4 s[2][4];
#pragma unroll
            for (int r2 = 0; r2 < 2; ++r2)
#pragma unroll
                for (int jt = 0; jt < 4; ++jt) { s[r2][jt][0] = 0.f; s[r2][jt][1] = 0.f; s[r2][jt][2] = 0.f; s[r2][jt][3] = 0.f; }
#pragma unroll
            for (int ks = 0; ks < 2; ++ks) {
                bf16x8 kf[4];
#pragma unroll
                for (int jt = 0; jt < 4; ++jt)
                    kf[jt] = *reinterpret_cast<const bf16x8*>(
                        &Kb[cur][(jt * 16 + l15) * 64 + (((ks * 4 + quad) ^ l7) * 8)]);
#pragma unroll
                for (int r2 = 0; r2 < 2; ++r2)
#pragma unroll
                    for (int jt = 0; jt < 4; ++jt)
                        s[r2][jt] = __builtin_amdgcn_mfma_f32_16x16x32_bf16(qf[rth * 2 + r2][ks], kf[jt], s[r2][jt], 0, 0, 0);
            }
#pragma unroll
            for (int r2 = 0; r2 < 2; ++r2) {
                const int rt = rth * 2 + r2;
#pragma unroll
                for (int jt = 0; jt < 4; ++jt) {
                    float2 f0 = __half22float2(__builtin_bit_cast(__half2, bl[cur][rt][jt].x));
                    float2 f1 = __half22float2(__builtin_bit_cast(__half2, bl[cur][rt][jt].y));
                    float bvr[4] = {f0.x, f0.y, f1.x, f1.y};
#pragma unroll
                    for (int reg = 0; reg < 4; ++reg) {
                        float p = fast_exp2(__builtin_fmaf(s[r2][jt][reg], kscale, bvr[reg]));
                        ps[(rt * 16 + quad * 4 + reg) * 72 + jt * 16 + l15] = f32_to_bf16(p);
                    }
                }
            }
        }

        // PV + row-sum (same-wave Ps round trip, no barrier needed)
#pragma unroll
        for (int ks = 0; ks < 2; ++ks) {
            bf16x8 vf[4];
#pragma unroll
            for (int nt = 0; nt < 4; ++nt)
                vf[nt] = *reinterpret_cast<const bf16x8*>(
                    &Vb[cur][(nt * 16 + l15) * 64 + (((ks * 4 + quad) ^ l7) * 8)]);
#pragma unroll
            for (int rt = 0; rt < 4; ++rt) {
                bf16x8 pf = *reinterpret_cast<const bf16x8*>(ps + (rt * 16 + l15) * 72 + ks * 32 + quad * 8);
#pragma unroll
                for (int nt = 0; nt < 4; ++nt)
                    o[rt][nt] = __builtin_amdgcn_mfma_f32_16x16x32_bf16(pf, vf[nt], o[rt][nt], 0, 0, 0);
                lacc[rt] = __builtin_amdgcn_mfma_f32_16x16x32_bf16(pf, ones, lacc[rt], 0, 0, 0);
            }
        }
    }

    // finalize: divide by l, write attn-out [B, N, H*64] bf16
#pragma unroll
    for (int rt = 0; rt < 4; ++rt) {
        float inv[4];
#pragma unroll
        for (int reg = 0; reg < 4; ++reg) inv[reg] = 1.f / lacc[rt][reg];
#pragma unroll
        for (int nt = 0; nt < 4; ++nt)
#pragma unroll
            for (int reg = 0; reg < 4; ++reg) {
                int row = b * 1024 + i0 + rt * 16 + quad * 4 + reg;
                int col = h * 64 + nt * 16 + l15;
                aout[(size_t)row * 512 + col] = f32_to_bf16(o[rt][nt][reg] * inv[reg]);
            }
    }
}

// ---------------------------------------------------------------------------
extern "C" void kernel_launch(void* const* d_in, const int* in_sizes, int n_in,
                              void* d_out, int out_size, void* d_ws, size_t ws_size,
                              hipStream_t stream) {
    const float* x          = (const float*)d_in[0];
    const float* Hstack     = (const float*)d_in[1];
    const float* hop_logits = (const float*)d_in[2];
    const float* rel_alpha  = (const float*)d_in[3];
    const float* Wqkv       = (const float*)d_in[4];
    const float* Wproj      = (const float*)d_in[5];
    const float* bproj      = (const float*)d_in[6];
    float* out = (float*)d_out;

    char* ws = (char*)d_ws;
    unsigned short* xb    = (unsigned short*)(ws);                  // x bf16        16 MB
    unsigned short* wqb   = (unsigned short*)(ws + 16777216);       // Wqkv bf16    1.5 MB
    unsigned short* wpb   = (unsigned short*)(ws + 18350080);       // Wproj bf16   0.5 MB
    unsigned short* qkvb  = (unsigned short*)(ws + 18874368);       // qkv bf16      48 MB
    unsigned short* vtb   = (unsigned short*)(ws + 69206016);       // V^T bf16      16 MB
    unsigned short* biast = (unsigned short*)(ws + 85983232);       // bias_t fp16   16 MB
    unsigned short* aoutb = (unsigned short*)(ws + 102760448);      // attn out bf16 16 MB

    // 1. converts
    cvt_f32_bf16<<<8192, 256, 0, stream>>>(x, xb, 2097152);
    cvt_f32_bf16<<<768, 256, 0, stream>>>(Wqkv, wqb, 196608);
    cvt_f32_bf16<<<256, 256, 0, stream>>>(Wproj, wpb, 65536);

    // 2. fused hop-bias -> fp16 tiled bias_t[h][i/32][j][i%32]
    bias_fused<<<dim3(16, 16, 8), 256, 0, stream>>>(Hstack, hop_logits, rel_alpha, (uint32_t*)biast);

    // 3. qkv = x @ Wqkv^T
    gemm_bt<true><<<dim3(128, 12), 256, 0, stream>>>(xb, wqb, qkvb, nullptr, 16384, 1536, 512);

    // 4. V transpose -> [B,H,64,N]
    transpose_v<<<dim3(16, 8, 16), 256, 0, stream>>>(qkvb, vtb);

    // 5. flash attention (Q-tile 256, dbuf) -> [B,N,512] bf16
    flash_attn<<<dim3(4, 8, 16), 256, 0, stream>>>(qkvb, vtb, biast, aoutb);

    // 6. out = attn_out @ Wproj^T + bproj  -> fp32
    gemm_bt<false><<<dim3(128, 4), 256, 0, stream>>>(aoutb, wpb, out, bproj, 16384, 512, 512);
}

// Round 5
// 255.158 us; speedup vs baseline: 1.0702x; 1.0702x over previous
//
#include <hip/hip_runtime.h>
#include <hip/hip_bf16.h>
#include <hip/hip_fp16.h>
#include <stdint.h>

// Problem constants (from reference)
#define DIM   512
#define NH    8
#define HD    64
#define NB    16
#define NTOK  1024
#define KHOPS 5

typedef __attribute__((ext_vector_type(8))) short bf16x8;   // 8 bf16 = 4 VGPR
typedef __attribute__((ext_vector_type(4))) float f32x4;

#define LOG2E 1.4426950408889634f

__device__ __forceinline__ unsigned short f32_to_bf16(float f) {
    unsigned int u = __builtin_bit_cast(unsigned int, f);
    unsigned int r = (u + 0x7FFFu + ((u >> 16) & 1u)) >> 16;   // RNE
    return (unsigned short)r;
}

__device__ __forceinline__ float fast_exp2(float x) {
    return __builtin_amdgcn_exp2f(x);
}

#define AS1C(p) ((const __attribute__((address_space(1))) void*)(p))
#define AS3(p)  ((__attribute__((address_space(3))) void*)(p))

// ---------------------------------------------------------------------------
// merged fp32 -> bf16 converts: x (8192 blocks), Wqkv (768), Wproj (256)
// ---------------------------------------------------------------------------
__global__ __launch_bounds__(256) void cvt_all(const float* __restrict__ x,
                                               const float* __restrict__ wq,
                                               const float* __restrict__ wp,
                                               unsigned short* __restrict__ xb,
                                               unsigned short* __restrict__ wqb,
                                               unsigned short* __restrict__ wpb) {
    int bid = blockIdx.x;
    const float* in; unsigned short* out; int i;
    if (bid < 8192)      { in = x;  out = xb;  i = bid * 256 + threadIdx.x; }
    else if (bid < 8960) { in = wq; out = wqb; i = (bid - 8192) * 256 + threadIdx.x; }
    else                 { in = wp; out = wpb; i = (bid - 8960) * 256 + threadIdx.x; }
    float4 v = reinterpret_cast<const float4*>(in)[i];
    ushort4 o;
    o.x = f32_to_bf16(v.x); o.y = f32_to_bf16(v.y);
    o.z = f32_to_bf16(v.z); o.w = f32_to_bf16(v.w);
    reinterpret_cast<ushort4*>(out)[i] = o;
}

// ---------------------------------------------------------------------------
// Fused hop-bias: biasT fp16 [h][i/32][j][i%32]
//   = rel_alpha[h]*LOG2E * sum_k softmax(hop_logits[h])[k] * H[k][i][j]
// ---------------------------------------------------------------------------
__global__ __launch_bounds__(256) void bias_fused(const float* __restrict__ H,
                                                  const float* __restrict__ hop_logits,
                                                  const float* __restrict__ rel_alpha,
                                                  uint32_t* __restrict__ biast) {
    __shared__ unsigned short Ls[64 * 76];
    const int tid = threadIdx.x;
    const int jt = blockIdx.x, it = blockIdx.y, h = blockIdx.z;
    const int j0 = jt * 64, i0 = it * 64;
    float cf[KHOPS];
    {
        float m = -1e30f;
#pragma unroll
        for (int k = 0; k < KHOPS; ++k) m = fmaxf(m, hop_logits[h * KHOPS + k]);
        float s = 0.f;
#pragma unroll
        for (int k = 0; k < KHOPS; ++k) { cf[k] = fast_exp2((hop_logits[h * KHOPS + k] - m) * LOG2E); s += cf[k]; }
        float ra = rel_alpha[h] * LOG2E / s;
#pragma unroll
        for (int k = 0; k < KHOPS; ++k) cf[k] *= ra;
    }
    const int r = tid >> 2, c0 = (tid & 3) * 16;
    float acc[16];
#pragma unroll
    for (int e = 0; e < 16; ++e) acc[e] = 0.f;
    for (int k = 0; k < KHOPS; ++k) {
        const float4* src = reinterpret_cast<const float4*>(
            H + (size_t)k * 1048576 + (size_t)(i0 + r) * 1024 + j0 + c0);
#pragma unroll
        for (int q = 0; q < 4; ++q) {
            float4 v = src[q];
            acc[q * 4 + 0] += cf[k] * v.x; acc[q * 4 + 1] += cf[k] * v.y;
            acc[q * 4 + 2] += cf[k] * v.z; acc[q * 4 + 3] += cf[k] * v.w;
        }
    }
#pragma unroll
    for (int q = 0; q < 4; ++q) {
        __half2 p0 = __floats2half2_rn(acc[q * 4 + 0], acc[q * 4 + 1]);
        __half2 p1 = __floats2half2_rn(acc[q * 4 + 2], acc[q * 4 + 3]);
        uint32_t* d = reinterpret_cast<uint32_t*>(&Ls[r * 76 + c0 + q * 4]);
        d[0] = __builtin_bit_cast(uint32_t, p0);
        d[1] = __builtin_bit_cast(uint32_t, p1);
    }
    __syncthreads();
    const int iw2 = tid & 15, jl = tid >> 4;
#pragma unroll
    for (int g = 0; g < 2; ++g)
#pragma unroll
        for (int t = 0; t < 4; ++t) {
            int j = t * 16 + jl;
            int i = g * 32 + iw2 * 2;
            uint32_t lo = (uint32_t)Ls[i * 76 + j] | ((uint32_t)Ls[(i + 1) * 76 + j] << 16);
            biast[(size_t)((h * 32 + (i0 >> 5) + g) * 1024 + (j0 + j)) * 16 + iw2] = lo;
        }
}

// ---------------------------------------------------------------------------
// gemm_qkv: C = xb @ Wqkv^T, M=16384, Nn=1536, K=512.
// Q/K column-blocks (n0<1024): bf16 row-major into qkv.
// V column-blocks (n0>=1024): written TRANSPOSED into vt[b][h][d][token]
// (C-layout: 4 consecutive regs = 4 consecutive tokens = one 8B store).
// The V region of qkv is never written.
// ---------------------------------------------------------------------------
__global__ __launch_bounds__(256) void gemm_qkv(const unsigned short* __restrict__ A,
                                                const unsigned short* __restrict__ Bw,
                                                unsigned short* __restrict__ qkv,
                                                unsigned short* __restrict__ vt) {
    __shared__ unsigned short As[128 * 32];
    __shared__ unsigned short Bs[128 * 32];
    const int tid  = threadIdx.x;
    const int lane = tid & 63;
    const int w    = tid >> 6;
    const int wr   = (w >> 1) * 64, wc = (w & 1) * 64;
    const int l15  = lane & 15, quad = lane >> 4;
    const int m0   = blockIdx.x * 128, n0 = blockIdx.y * 128;
    const int K = 512, Nn = 1536;

    f32x4 acc[4][4];
#pragma unroll
    for (int i = 0; i < 4; ++i)
#pragma unroll
        for (int j = 0; j < 4; ++j) { acc[i][j][0] = 0.f; acc[i][j][1] = 0.f; acc[i][j][2] = 0.f; acc[i][j][3] = 0.f; }

    for (int k0 = 0; k0 < K; k0 += 32) {
        __syncthreads();
#pragma unroll
        for (int t = 0; t < 2; ++t) {
            int c = t * 256 + w * 64 + lane;
            int r = c >> 2, kh = c & 3;
            const unsigned short* ga = A  + (size_t)(m0 + r) * K + k0 + kh * 8;
            const unsigned short* gb = Bw + (size_t)(n0 + r) * K + k0 + kh * 8;
            __builtin_amdgcn_global_load_lds(AS1C(ga), AS3(&As[(t * 256 + w * 64) * 8]), 16, 0, 0);
            __builtin_amdgcn_global_load_lds(AS1C(gb), AS3(&Bs[(t * 256 + w * 64) * 8]), 16, 0, 0);
        }
        __syncthreads();
        bf16x8 af[4], bfr[4];
#pragma unroll
        for (int rt = 0; rt < 4; ++rt)
            af[rt] = *reinterpret_cast<const bf16x8*>(&As[(wr + rt * 16 + l15) * 32 + quad * 8]);
#pragma unroll
        for (int ct = 0; ct < 4; ++ct)
            bfr[ct] = *reinterpret_cast<const bf16x8*>(&Bs[(wc + ct * 16 + l15) * 32 + quad * 8]);
#pragma unroll
        for (int rt = 0; rt < 4; ++rt)
#pragma unroll
            for (int ct = 0; ct < 4; ++ct)
                acc[rt][ct] = __builtin_amdgcn_mfma_f32_16x16x32_bf16(af[rt], bfr[ct], acc[rt][ct], 0, 0, 0);
    }

    if (n0 < 1024) {
        // Q/K: row-major bf16 into qkv
#pragma unroll
        for (int rt = 0; rt < 4; ++rt)
#pragma unroll
            for (int ct = 0; ct < 4; ++ct)
#pragma unroll
                for (int reg = 0; reg < 4; ++reg) {
                    int row = m0 + wr + rt * 16 + quad * 4 + reg;
                    int col = n0 + wc + ct * 16 + l15;
                    qkv[(size_t)row * Nn + col] = f32_to_bf16(acc[rt][ct][reg]);
                }
    } else {
        // V: transposed into vt[b][h][d][token]
        const int b = m0 >> 10;
#pragma unroll
        for (int ct = 0; ct < 4; ++ct) {
            int c = n0 - 1024 + wc + ct * 16 + l15;   // h*64+d
            unsigned short* vrow = vt + ((size_t)(b * 8) * 64 + c) * 1024;
#pragma unroll
            for (int rt = 0; rt < 4; ++rt) {
                int trow = (m0 & 1023) + wr + rt * 16 + quad * 4;
                ushort4 pk;
                pk.x = f32_to_bf16(acc[rt][ct][0]);
                pk.y = f32_to_bf16(acc[rt][ct][1]);
                pk.z = f32_to_bf16(acc[rt][ct][2]);
                pk.w = f32_to_bf16(acc[rt][ct][3]);
                *reinterpret_cast<ushort4*>(vrow + trow) = pk;
            }
        }
    }
}

// ---------------------------------------------------------------------------
// GEMM  C[M,Nn] = A[M,K] * Bw[Nn,K]^T, fp32 out + bias (projection)
// ---------------------------------------------------------------------------
__global__ __launch_bounds__(256) void gemm_proj(const unsigned short* __restrict__ A,
                                                 const unsigned short* __restrict__ Bw,
                                                 float* __restrict__ C,
                                                 const float* __restrict__ cbias,
                                                 int M, int Nn, int K) {
    __shared__ unsigned short As[128 * 32];
    __shared__ unsigned short Bs[128 * 32];
    const int tid  = threadIdx.x;
    const int lane = tid & 63;
    const int w    = tid >> 6;
    const int wr   = (w >> 1) * 64, wc = (w & 1) * 64;
    const int l15  = lane & 15, quad = lane >> 4;
    const int m0   = blockIdx.x * 128, n0 = blockIdx.y * 128;

    f32x4 acc[4][4];
#pragma unroll
    for (int i = 0; i < 4; ++i)
#pragma unroll
        for (int j = 0; j < 4; ++j) { acc[i][j][0] = 0.f; acc[i][j][1] = 0.f; acc[i][j][2] = 0.f; acc[i][j][3] = 0.f; }

    for (int k0 = 0; k0 < K; k0 += 32) {
        __syncthreads();
#pragma unroll
        for (int t = 0; t < 2; ++t) {
            int c = t * 256 + w * 64 + lane;
            int r = c >> 2, kh = c & 3;
            const unsigned short* ga = A  + (size_t)(m0 + r) * K + k0 + kh * 8;
            const unsigned short* gb = Bw + (size_t)(n0 + r) * K + k0 + kh * 8;
            __builtin_amdgcn_global_load_lds(AS1C(ga), AS3(&As[(t * 256 + w * 64) * 8]), 16, 0, 0);
            __builtin_amdgcn_global_load_lds(AS1C(gb), AS3(&Bs[(t * 256 + w * 64) * 8]), 16, 0, 0);
        }
        __syncthreads();
        bf16x8 af[4], bfr[4];
#pragma unroll
        for (int rt = 0; rt < 4; ++rt)
            af[rt] = *reinterpret_cast<const bf16x8*>(&As[(wr + rt * 16 + l15) * 32 + quad * 8]);
#pragma unroll
        for (int ct = 0; ct < 4; ++ct)
            bfr[ct] = *reinterpret_cast<const bf16x8*>(&Bs[(wc + ct * 16 + l15) * 32 + quad * 8]);
#pragma unroll
        for (int rt = 0; rt < 4; ++rt)
#pragma unroll
            for (int ct = 0; ct < 4; ++ct)
                acc[rt][ct] = __builtin_amdgcn_mfma_f32_16x16x32_bf16(af[rt], bfr[ct], acc[rt][ct], 0, 0, 0);
    }

#pragma unroll
    for (int ct = 0; ct < 4; ++ct) {
        int col = n0 + wc + ct * 16 + l15;
        float bv = cbias[col];
#pragma unroll
        for (int rt = 0; rt < 4; ++rt)
#pragma unroll
            for (int reg = 0; reg < 4; ++reg) {
                int row = m0 + wr + rt * 16 + quad * 4 + reg;
                C[(size_t)row * Nn + col] = acc[rt][ct][reg] + bv;
            }
    }
}

// ---------------------------------------------------------------------------
// Flash attention (R3 structure) with XCD-aware grid: blockIdx.x = h so all
// qt-blocks sharing one (h,b) K/V slice and one head's 2MB bias land on the
// same XCD (linear%8 == h). LDS-staged K/V (global_load_lds w16, XOR chunk
// swizzle), dense tiled bias loads, no-max softmax, row sums via ones-MFMA.
// ---------------------------------------------------------------------------
__global__ __launch_bounds__(256, 3) void flash_attn(const unsigned short* __restrict__ qkv,
                                                     const unsigned short* __restrict__ vt,
                                                     const unsigned short* __restrict__ biast,
                                                     unsigned short* __restrict__ aout) {
    __shared__ unsigned short Kb[64 * 64];
    __shared__ unsigned short Vb[64 * 64];
    __shared__ unsigned short Ps[4 * 32 * 72];
    const int tid  = threadIdx.x;
    const int lane = tid & 63, w = tid >> 6;
    const int l15  = lane & 15, quad = lane >> 4;
    const int h = blockIdx.x, qt = blockIdx.y, b = blockIdx.z;   // x=h: XCD locality
    const int i0 = qt * 128 + w * 32;
    const float kscale = 0.125f * LOG2E;
    const int l7 = l15 & 7;

    // Q fragments: A[m=lane&15][k=quad*8+j]
    bf16x8 qf[2][2];
#pragma unroll
    for (int rt = 0; rt < 2; ++rt)
#pragma unroll
        for (int ks = 0; ks < 2; ++ks)
            qf[rt][ks] = *reinterpret_cast<const bf16x8*>(
                qkv + (size_t)(b * 1024 + i0 + rt * 16 + l15) * 1536 + h * 64 + ks * 32 + quad * 8);

    f32x4 o[2][4];
    f32x4 lacc[2];
#pragma unroll
    for (int rt = 0; rt < 2; ++rt) {
#pragma unroll
        for (int nt = 0; nt < 4; ++nt) { o[rt][nt][0] = 0.f; o[rt][nt][1] = 0.f; o[rt][nt][2] = 0.f; o[rt][nt][3] = 0.f; }
        lacc[rt][0] = 0.f; lacc[rt][1] = 0.f; lacc[rt][2] = 0.f; lacc[rt][3] = 0.f;
    }

    bf16x8 ones;
#pragma unroll
    for (int e = 0; e < 8; ++e) ones[e] = (short)0x3F80;   // bf16 1.0

    const int srow = lane >> 3;
    const int gch  = (lane & 7) ^ (srow & 7);
    const unsigned short* kgbase = qkv + (size_t)b * 1024 * 1536 + 512 + h * 64 + gch * 8;
    const unsigned short* vgbase = vt + (size_t)((b * 8 + h) * 64) * 1024 + gch * 8;
    const unsigned short* bb = biast + ((size_t)(h * 32 + qt * 4 + w) * 1024) * 32 + quad * 4;
    unsigned short* ps = &Ps[w * 32 * 72];

    for (int j0 = 0; j0 < 1024; j0 += 64) {
        __syncthreads();   // previous tile fully consumed
#pragma unroll
        for (int t = 0; t < 2; ++t) {
            int rl = w * 16 + t * 8 + srow;
            __builtin_amdgcn_global_load_lds(AS1C(kgbase + (size_t)(j0 + rl) * 1536),
                                             AS3(&Kb[(w * 16 + t * 8) * 64]), 16, 0, 0);
            __builtin_amdgcn_global_load_lds(AS1C(vgbase + (size_t)rl * 1024 + j0),
                                             AS3(&Vb[(w * 16 + t * 8) * 64]), 16, 0, 0);
        }
        uint2 bl[2][4];
#pragma unroll
        for (int rt = 0; rt < 2; ++rt)
#pragma unroll
            for (int jt = 0; jt < 4; ++jt)
                bl[rt][jt] = *reinterpret_cast<const uint2*>(
                    bb + (size_t)(j0 + jt * 16 + l15) * 32 + rt * 16);
        __syncthreads();   // staging visible

        // S = Q K^T
        f32x4 s[2][4];
#pragma unroll
        for (int rt = 0; rt < 2; ++rt)
#pragma unroll
            for (int jt = 0; jt < 4; ++jt) { s[rt][jt][0] = 0.f; s[rt][jt][1] = 0.f; s[rt][jt][2] = 0.f; s[rt][jt][3] = 0.f; }
#pragma unroll
        for (int ks = 0; ks < 2; ++ks) {
            bf16x8 kf[4];
#pragma unroll
            for (int jt = 0; jt < 4; ++jt)
                kf[jt] = *reinterpret_cast<const bf16x8*>(
                    &Kb[(jt * 16 + l15) * 64 + (((ks * 4 + quad) ^ l7) * 8)]);
#pragma unroll
            for (int rt = 0; rt < 2; ++rt)
#pragma unroll
                for (int jt = 0; jt < 4; ++jt)
                    s[rt][jt] = __builtin_amdgcn_mfma_f32_16x16x32_bf16(qf[rt][ks], kf[jt], s[rt][jt], 0, 0, 0);
        }

        // p = exp2(s*kscale + bias)
#pragma unroll
        for (int rt = 0; rt < 2; ++rt)
#pragma unroll
            for (int jt = 0; jt < 4; ++jt) {
                float2 f0 = __half22float2(__builtin_bit_cast(__half2, bl[rt][jt].x));
                float2 f1 = __half22float2(__builtin_bit_cast(__half2, bl[rt][jt].y));
                float bvr[4] = {f0.x, f0.y, f1.x, f1.y};
#pragma unroll
                for (int reg = 0; reg < 4; ++reg) {
                    float p = fast_exp2(__builtin_fmaf(s[rt][jt][reg], kscale, bvr[reg]));
                    ps[(rt * 16 + quad * 4 + reg) * 72 + jt * 16 + l15] = f32_to_bf16(p);
                }
            }

        // PV + row-sum
#pragma unroll
        for (int ks = 0; ks < 2; ++ks) {
            bf16x8 pf[2], vf[4];
#pragma unroll
            for (int rt = 0; rt < 2; ++rt)
                pf[rt] = *reinterpret_cast<const bf16x8*>(ps + (rt * 16 + l15) * 72 + ks * 32 + quad * 8);
#pragma unroll
            for (int nt = 0; nt < 4; ++nt)
                vf[nt] = *reinterpret_cast<const bf16x8*>(
                    &Vb[(nt * 16 + l15) * 64 + (((ks * 4 + quad) ^ l7) * 8)]);
#pragma unroll
            for (int rt = 0; rt < 2; ++rt) {
#pragma unroll
                for (int nt = 0; nt < 4; ++nt)
                    o[rt][nt] = __builtin_amdgcn_mfma_f32_16x16x32_bf16(pf[rt], vf[nt], o[rt][nt], 0, 0, 0);
                lacc[rt] = __builtin_amdgcn_mfma_f32_16x16x32_bf16(pf[rt], ones, lacc[rt], 0, 0, 0);
            }
        }
    }

    // finalize
#pragma unroll
    for (int rt = 0; rt < 2; ++rt) {
        float inv[4];
#pragma unroll
        for (int reg = 0; reg < 4; ++reg) inv[reg] = 1.f / lacc[rt][reg];
#pragma unroll
        for (int nt = 0; nt < 4; ++nt)
#pragma unroll
            for (int reg = 0; reg < 4; ++reg) {
                int row = b * 1024 + i0 + rt * 16 + quad * 4 + reg;
                int col = h * 64 + nt * 16 + l15;
                aout[(size_t)row * 512 + col] = f32_to_bf16(o[rt][nt][reg] * inv[reg]);
            }
    }
}

// ---------------------------------------------------------------------------
extern "C" void kernel_launch(void* const* d_in, const int* in_sizes, int n_in,
                              void* d_out, int out_size, void* d_ws, size_t ws_size,
                              hipStream_t stream) {
    const float* x          = (const float*)d_in[0];
    const float* Hstack     = (const float*)d_in[1];
    const float* hop_logits = (const float*)d_in[2];
    const float* rel_alpha  = (const float*)d_in[3];
    const float* Wqkv       = (const float*)d_in[4];
    const float* Wproj      = (const float*)d_in[5];
    const float* bproj      = (const float*)d_in[6];
    float* out = (float*)d_out;

    char* ws = (char*)d_ws;
    unsigned short* xb    = (unsigned short*)(ws);                  // x bf16        16 MB
    unsigned short* wqb   = (unsigned short*)(ws + 16777216);       // Wqkv bf16    1.5 MB
    unsigned short* wpb   = (unsigned short*)(ws + 18350080);       // Wproj bf16   0.5 MB
    unsigned short* qkvb  = (unsigned short*)(ws + 18874368);       // qkv bf16 (Q,K only used)  48 MB
    unsigned short* vtb   = (unsigned short*)(ws + 69206016);       // V^T bf16      16 MB
    unsigned short* biast = (unsigned short*)(ws + 85983232);       // bias_t fp16   16 MB
    unsigned short* aoutb = (unsigned short*)(ws + 102760448);      // attn out bf16 16 MB

    // 1. merged converts
    cvt_all<<<9216, 256, 0, stream>>>(x, Wqkv, Wproj, xb, wqb, wpb);

    // 2. fused hop-bias -> fp16 tiled bias_t[h][i/32][j][i%32]
    bias_fused<<<dim3(16, 16, 8), 256, 0, stream>>>(Hstack, hop_logits, rel_alpha, (uint32_t*)biast);

    // 3. qkv GEMM; V columns written transposed straight into vt
    gemm_qkv<<<dim3(128, 12), 256, 0, stream>>>(xb, wqb, qkvb, vtb);

    // 4. flash attention -> [B,N,512] bf16  (grid x=h for XCD locality)
    flash_attn<<<dim3(8, 8, 16), 256, 0, stream>>>(qkvb, vtb, biast, aoutb);

    // 5. out = attn_out @ Wproj^T + bproj  -> fp32
    gemm_proj<<<dim3(128, 4), 256, 0, stream>>>(aoutb, wpb, out, bproj, 16384, 512, 512);
}

// Round 6
// 241.121 us; speedup vs baseline: 1.1325x; 1.0582x over previous
//
#include <hip/hip_runtime.h>
#include <hip/hip_bf16.h>
#include <hip/hip_fp16.h>
#include <stdint.h>

// Problem constants (from reference)
#define DIM   512
#define NH    8
#define HD    64
#define NB    16
#define NTOK  1024
#define KHOPS 5

typedef __attribute__((ext_vector_type(8))) short bf16x8;   // 8 bf16 = 4 VGPR
typedef __attribute__((ext_vector_type(4))) float f32x4;

#define LOG2E 1.4426950408889634f

__device__ __forceinline__ unsigned short f32_to_bf16(float f) {
    unsigned int u = __builtin_bit_cast(unsigned int, f);
    unsigned int r = (u + 0x7FFFu + ((u >> 16) & 1u)) >> 16;   // RNE
    return (unsigned short)r;
}

__device__ __forceinline__ float fast_exp2(float x) {
    return __builtin_amdgcn_exp2f(x);
}

#define AS1C(p) ((const __attribute__((address_space(1))) void*)(p))
#define AS3(p)  ((__attribute__((address_space(3))) void*)(p))

// ---------------------------------------------------------------------------
// merged fp32 -> bf16 converts: x (8192 blocks), Wqkv (768), Wproj (256)
// ---------------------------------------------------------------------------
__global__ __launch_bounds__(256) void cvt_all(const float* __restrict__ x,
                                               const float* __restrict__ wq,
                                               const float* __restrict__ wp,
                                               unsigned short* __restrict__ xb,
                                               unsigned short* __restrict__ wqb,
                                               unsigned short* __restrict__ wpb) {
    int bid = blockIdx.x;
    const float* in; unsigned short* out; int i;
    if (bid < 8192)      { in = x;  out = xb;  i = bid * 256 + threadIdx.x; }
    else if (bid < 8960) { in = wq; out = wqb; i = (bid - 8192) * 256 + threadIdx.x; }
    else                 { in = wp; out = wpb; i = (bid - 8960) * 256 + threadIdx.x; }
    float4 v = reinterpret_cast<const float4*>(in)[i];
    ushort4 o;
    o.x = f32_to_bf16(v.x); o.y = f32_to_bf16(v.y);
    o.z = f32_to_bf16(v.z); o.w = f32_to_bf16(v.w);
    reinterpret_cast<ushort4*>(out)[i] = o;
}

// ---------------------------------------------------------------------------
// Fused hop-bias, ALL 8 HEADS per block: biasT fp16 [h][i/32][j][i%32]
//   = rel_alpha[h]*LOG2E * sum_k softmax(hop_logits[h])[k] * H[k][i][j]
// One block per (jt,it): H tile (5 x 64x64) read ONCE into registers
// (16 floats/hop/thread), then per-head combine + LDS transpose + write.
// H fetch: 256 blocks x 80KB = 20MB (was 160MB when h was a grid dim).
// ---------------------------------------------------------------------------
__global__ __launch_bounds__(256) void bias_fused(const float* __restrict__ H,
                                                  const float* __restrict__ hop_logits,
                                                  const float* __restrict__ rel_alpha,
                                                  uint32_t* __restrict__ biast) {
    __shared__ unsigned short Ls[64 * 76];
    const int tid = threadIdx.x;
    const int jt = blockIdx.x, it = blockIdx.y;
    const int j0 = jt * 64, i0 = it * 64;
    // softmax coefficients for all heads (scalar-cached loads, cheap)
    float cf[NH][KHOPS];
#pragma unroll
    for (int h = 0; h < NH; ++h) {
        float m = -1e30f;
#pragma unroll
        for (int k = 0; k < KHOPS; ++k) m = fmaxf(m, hop_logits[h * KHOPS + k]);
        float s = 0.f;
#pragma unroll
        for (int k = 0; k < KHOPS; ++k) { cf[h][k] = fast_exp2((hop_logits[h * KHOPS + k] - m) * LOG2E); s += cf[h][k]; }
        float ra = rel_alpha[h] * LOG2E / s;
#pragma unroll
        for (int k = 0; k < KHOPS; ++k) cf[h][k] *= ra;
    }
    const int r = tid >> 2, c0 = (tid & 3) * 16;
    // load H tile: 16 floats per hop per thread (held across all heads)
    float hv[KHOPS][16];
#pragma unroll
    for (int k = 0; k < KHOPS; ++k) {
        const float4* src = reinterpret_cast<const float4*>(
            H + (size_t)k * 1048576 + (size_t)(i0 + r) * 1024 + j0 + c0);
#pragma unroll
        for (int q = 0; q < 4; ++q) {
            float4 v = src[q];
            hv[k][q * 4 + 0] = v.x; hv[k][q * 4 + 1] = v.y;
            hv[k][q * 4 + 2] = v.z; hv[k][q * 4 + 3] = v.w;
        }
    }
    const int iw2 = tid & 15, jl = tid >> 4;
    for (int h = 0; h < NH; ++h) {
#pragma unroll
        for (int q = 0; q < 4; ++q) {
            float a0 = 0.f, a1 = 0.f, a2 = 0.f, a3 = 0.f;
#pragma unroll
            for (int k = 0; k < KHOPS; ++k) {
                a0 += cf[h][k] * hv[k][q * 4 + 0];
                a1 += cf[h][k] * hv[k][q * 4 + 1];
                a2 += cf[h][k] * hv[k][q * 4 + 2];
                a3 += cf[h][k] * hv[k][q * 4 + 3];
            }
            __half2 p0 = __floats2half2_rn(a0, a1);
            __half2 p1 = __floats2half2_rn(a2, a3);
            uint32_t* d = reinterpret_cast<uint32_t*>(&Ls[r * 76 + c0 + q * 4]);
            d[0] = __builtin_bit_cast(uint32_t, p0);
            d[1] = __builtin_bit_cast(uint32_t, p1);
        }
        __syncthreads();
#pragma unroll
        for (int g = 0; g < 2; ++g)
#pragma unroll
            for (int t = 0; t < 4; ++t) {
                int j = t * 16 + jl;
                int i = g * 32 + iw2 * 2;
                uint32_t lo = (uint32_t)Ls[i * 76 + j] | ((uint32_t)Ls[(i + 1) * 76 + j] << 16);
                biast[(size_t)((h * 32 + (i0 >> 5) + g) * 1024 + (j0 + j)) * 16 + iw2] = lo;
            }
        __syncthreads();
    }
}

// ---------------------------------------------------------------------------
// gemm_qkv: C = xb @ Wqkv^T, M=16384, Nn=1536, K=512. 1D grid, XCD-partitioned:
// xcd = b&7 owns m-tiles [xcd*16, xcd*16+16) for all 12 n -> A slice (2MB)
// stays L2-resident per XCD. V column-blocks written transposed into vt.
// ---------------------------------------------------------------------------
__global__ __launch_bounds__(256) void gemm_qkv(const unsigned short* __restrict__ A,
                                                const unsigned short* __restrict__ Bw,
                                                unsigned short* __restrict__ qkv,
                                                unsigned short* __restrict__ vt) {
    __shared__ unsigned short As[128 * 32];
    __shared__ unsigned short Bs[128 * 32];
    const int tid  = threadIdx.x;
    const int lane = tid & 63;
    const int w    = tid >> 6;
    const int wr   = (w >> 1) * 64, wc = (w & 1) * 64;
    const int l15  = lane & 15, quad = lane >> 4;
    const int bid  = blockIdx.x;
    const int xcd  = bid & 7, slot = bid >> 3;
    const int m0   = (xcd * 16 + (slot & 15)) * 128;
    const int n0   = (slot >> 4) * 128;
    const int K = 512, Nn = 1536;

    f32x4 acc[4][4];
#pragma unroll
    for (int i = 0; i < 4; ++i)
#pragma unroll
        for (int j = 0; j < 4; ++j) { acc[i][j][0] = 0.f; acc[i][j][1] = 0.f; acc[i][j][2] = 0.f; acc[i][j][3] = 0.f; }

    for (int k0 = 0; k0 < K; k0 += 32) {
        __syncthreads();
#pragma unroll
        for (int t = 0; t < 2; ++t) {
            int c = t * 256 + w * 64 + lane;
            int r = c >> 2, kh = c & 3;
            const unsigned short* ga = A  + (size_t)(m0 + r) * K + k0 + kh * 8;
            const unsigned short* gb = Bw + (size_t)(n0 + r) * K + k0 + kh * 8;
            __builtin_amdgcn_global_load_lds(AS1C(ga), AS3(&As[(t * 256 + w * 64) * 8]), 16, 0, 0);
            __builtin_amdgcn_global_load_lds(AS1C(gb), AS3(&Bs[(t * 256 + w * 64) * 8]), 16, 0, 0);
        }
        __syncthreads();
        bf16x8 af[4], bfr[4];
#pragma unroll
        for (int rt = 0; rt < 4; ++rt)
            af[rt] = *reinterpret_cast<const bf16x8*>(&As[(wr + rt * 16 + l15) * 32 + quad * 8]);
#pragma unroll
        for (int ct = 0; ct < 4; ++ct)
            bfr[ct] = *reinterpret_cast<const bf16x8*>(&Bs[(wc + ct * 16 + l15) * 32 + quad * 8]);
#pragma unroll
        for (int rt = 0; rt < 4; ++rt)
#pragma unroll
            for (int ct = 0; ct < 4; ++ct)
                acc[rt][ct] = __builtin_amdgcn_mfma_f32_16x16x32_bf16(af[rt], bfr[ct], acc[rt][ct], 0, 0, 0);
    }

    if (n0 < 1024) {
        // Q/K: row-major bf16 into qkv
#pragma unroll
        for (int rt = 0; rt < 4; ++rt)
#pragma unroll
            for (int ct = 0; ct < 4; ++ct)
#pragma unroll
                for (int reg = 0; reg < 4; ++reg) {
                    int row = m0 + wr + rt * 16 + quad * 4 + reg;
                    int col = n0 + wc + ct * 16 + l15;
                    qkv[(size_t)row * Nn + col] = f32_to_bf16(acc[rt][ct][reg]);
                }
    } else {
        // V: transposed into vt[b][h][d][token]
        const int b = m0 >> 10;
#pragma unroll
        for (int ct = 0; ct < 4; ++ct) {
            int c = n0 - 1024 + wc + ct * 16 + l15;   // h*64+d
            unsigned short* vrow = vt + ((size_t)(b * 8) * 64 + c) * 1024;
#pragma unroll
            for (int rt = 0; rt < 4; ++rt) {
                int trow = (m0 & 1023) + wr + rt * 16 + quad * 4;
                ushort4 pk;
                pk.x = f32_to_bf16(acc[rt][ct][0]);
                pk.y = f32_to_bf16(acc[rt][ct][1]);
                pk.z = f32_to_bf16(acc[rt][ct][2]);
                pk.w = f32_to_bf16(acc[rt][ct][3]);
                *reinterpret_cast<ushort4*>(vrow + trow) = pk;
            }
        }
    }
}

// ---------------------------------------------------------------------------
// gemm_proj: out = aout @ Wproj^T + bproj, fp32 out. Same XCD partition:
// xcd owns m-tiles [xcd*16, xcd*16+16) for all 4 n-tiles.
// ---------------------------------------------------------------------------
__global__ __launch_bounds__(256) void gemm_proj(const unsigned short* __restrict__ A,
                                                 const unsigned short* __restrict__ Bw,
                                                 float* __restrict__ C,
                                                 const float* __restrict__ cbias) {
    __shared__ unsigned short As[128 * 32];
    __shared__ unsigned short Bs[128 * 32];
    const int tid  = threadIdx.x;
    const int lane = tid & 63;
    const int w    = tid >> 6;
    const int wr   = (w >> 1) * 64, wc = (w & 1) * 64;
    const int l15  = lane & 15, quad = lane >> 4;
    const int bid  = blockIdx.x;
    const int xcd  = bid & 7, slot = bid >> 3;
    const int m0   = (xcd * 16 + (slot & 15)) * 128;
    const int n0   = (slot >> 4) * 128;
    const int K = 512, Nn = 512;

    f32x4 acc[4][4];
#pragma unroll
    for (int i = 0; i < 4; ++i)
#pragma unroll
        for (int j = 0; j < 4; ++j) { acc[i][j][0] = 0.f; acc[i][j][1] = 0.f; acc[i][j][2] = 0.f; acc[i][j][3] = 0.f; }

    for (int k0 = 0; k0 < K; k0 += 32) {
        __syncthreads();
#pragma unroll
        for (int t = 0; t < 2; ++t) {
            int c = t * 256 + w * 64 + lane;
            int r = c >> 2, kh = c & 3;
            const unsigned short* ga = A  + (size_t)(m0 + r) * K + k0 + kh * 8;
            const unsigned short* gb = Bw + (size_t)(n0 + r) * K + k0 + kh * 8;
            __builtin_amdgcn_global_load_lds(AS1C(ga), AS3(&As[(t * 256 + w * 64) * 8]), 16, 0, 0);
            __builtin_amdgcn_global_load_lds(AS1C(gb), AS3(&Bs[(t * 256 + w * 64) * 8]), 16, 0, 0);
        }
        __syncthreads();
        bf16x8 af[4], bfr[4];
#pragma unroll
        for (int rt = 0; rt < 4; ++rt)
            af[rt] = *reinterpret_cast<const bf16x8*>(&As[(wr + rt * 16 + l15) * 32 + quad * 8]);
#pragma unroll
        for (int ct = 0; ct < 4; ++ct)
            bfr[ct] = *reinterpret_cast<const bf16x8*>(&Bs[(wc + ct * 16 + l15) * 32 + quad * 8]);
#pragma unroll
        for (int rt = 0; rt < 4; ++rt)
#pragma unroll
            for (int ct = 0; ct < 4; ++ct)
                acc[rt][ct] = __builtin_amdgcn_mfma_f32_16x16x32_bf16(af[rt], bfr[ct], acc[rt][ct], 0, 0, 0);
    }

#pragma unroll
    for (int ct = 0; ct < 4; ++ct) {
        int col = n0 + wc + ct * 16 + l15;
        float bv = cbias[col];
#pragma unroll
        for (int rt = 0; rt < 4; ++rt)
#pragma unroll
            for (int reg = 0; reg < 4; ++reg) {
                int row = m0 + wr + rt * 16 + quad * 4 + reg;
                C[(size_t)row * Nn + col] = acc[rt][ct][reg] + bv;
            }
    }
}

// ---------------------------------------------------------------------------
// Flash attention v6: R5 structure + double-buffered K/V LDS staging.
// global_load_lds costs no data VGPRs, so dbuf adds zero register pressure
// (R4's spills came from bias-register prefetch, not the dbuf). One barrier
// per j-tile: prefetch for tile it+1 issued right after the barrier; the
// compiler's vmcnt(0)+barrier drain at tile it+1 lands a full compute phase
// after issue. Grid x=h for XCD locality (R5's 4x FETCH win).
// ---------------------------------------------------------------------------
__global__ __launch_bounds__(256, 3) void flash_attn(const unsigned short* __restrict__ qkv,
                                                     const unsigned short* __restrict__ vt,
                                                     const unsigned short* __restrict__ biast,
                                                     unsigned short* __restrict__ aout) {
    __shared__ unsigned short Kb[2][64 * 64];
    __shared__ unsigned short Vb[2][64 * 64];
    __shared__ unsigned short Ps[4 * 32 * 72];
    const int tid  = threadIdx.x;
    const int lane = tid & 63, w = tid >> 6;
    const int l15  = lane & 15, quad = lane >> 4;
    const int h = blockIdx.x, qt = blockIdx.y, b = blockIdx.z;   // x=h: XCD locality
    const int i0 = qt * 128 + w * 32;
    const float kscale = 0.125f * LOG2E;
    const int l7 = l15 & 7;

    // Q fragments: A[m=lane&15][k=quad*8+j]
    bf16x8 qf[2][2];
#pragma unroll
    for (int rt = 0; rt < 2; ++rt)
#pragma unroll
        for (int ks = 0; ks < 2; ++ks)
            qf[rt][ks] = *reinterpret_cast<const bf16x8*>(
                qkv + (size_t)(b * 1024 + i0 + rt * 16 + l15) * 1536 + h * 64 + ks * 32 + quad * 8);

    f32x4 o[2][4];
    f32x4 lacc[2];
#pragma unroll
    for (int rt = 0; rt < 2; ++rt) {
#pragma unroll
        for (int nt = 0; nt < 4; ++nt) { o[rt][nt][0] = 0.f; o[rt][nt][1] = 0.f; o[rt][nt][2] = 0.f; o[rt][nt][3] = 0.f; }
        lacc[rt][0] = 0.f; lacc[rt][1] = 0.f; lacc[rt][2] = 0.f; lacc[rt][3] = 0.f;
    }

    bf16x8 ones;
#pragma unroll
    for (int e = 0; e < 8; ++e) ones[e] = (short)0x3F80;   // bf16 1.0

    const int srow = lane >> 3;
    const int gch  = (lane & 7) ^ srow;
    const unsigned short* kgbase = qkv + (size_t)b * 1024 * 1536 + 512 + h * 64 + gch * 8;
    const unsigned short* vgbase = vt + (size_t)((b * 8 + h) * 64) * 1024 + gch * 8;
    const unsigned short* bb = biast + ((size_t)(h * 32 + qt * 4 + w) * 1024) * 32 + quad * 4;
    unsigned short* ps = &Ps[w * 32 * 72];

    // prologue: stage tile 0 into buffer 0
#pragma unroll
    for (int t = 0; t < 2; ++t) {
        int rl = w * 16 + t * 8 + srow;
        __builtin_amdgcn_global_load_lds(AS1C(kgbase + (size_t)rl * 1536),
                                         AS3(&Kb[0][(w * 16 + t * 8) * 64]), 16, 0, 0);
        __builtin_amdgcn_global_load_lds(AS1C(vgbase + (size_t)rl * 1024),
                                         AS3(&Vb[0][(w * 16 + t * 8) * 64]), 16, 0, 0);
    }

#pragma unroll 2
    for (int it = 0; it < 16; ++it) {
        const int cur = it & 1, nxt = cur ^ 1;
        const int j0 = it * 64;
        __syncthreads();   // drains prefetch (issued a full compute phase ago); frees buf[nxt]

        if (it < 15) {
            const int j0n = j0 + 64;
#pragma unroll
            for (int t = 0; t < 2; ++t) {
                int rl = w * 16 + t * 8 + srow;
                __builtin_amdgcn_global_load_lds(AS1C(kgbase + (size_t)(j0n + rl) * 1536),
                                                 AS3(&Kb[nxt][(w * 16 + t * 8) * 64]), 16, 0, 0);
                __builtin_amdgcn_global_load_lds(AS1C(vgbase + (size_t)rl * 1024 + j0n),
                                                 AS3(&Vb[nxt][(w * 16 + t * 8) * 64]), 16, 0, 0);
            }
        }

        uint2 bl[2][4];
#pragma unroll
        for (int rt = 0; rt < 2; ++rt)
#pragma unroll
            for (int jt = 0; jt < 4; ++jt)
                bl[rt][jt] = *reinterpret_cast<const uint2*>(
                    bb + (size_t)(j0 + jt * 16 + l15) * 32 + rt * 16);

        // S = Q K^T
        f32x4 s[2][4];
#pragma unroll
        for (int rt = 0; rt < 2; ++rt)
#pragma unroll
            for (int jt = 0; jt < 4; ++jt) { s[rt][jt][0] = 0.f; s[rt][jt][1] = 0.f; s[rt][jt][2] = 0.f; s[rt][jt][3] = 0.f; }
#pragma unroll
        for (int ks = 0; ks < 2; ++ks) {
            bf16x8 kf[4];
#pragma unroll
            for (int jt = 0; jt < 4; ++jt)
                kf[jt] = *reinterpret_cast<const bf16x8*>(
                    &Kb[cur][(jt * 16 + l15) * 64 + (((ks * 4 + quad) ^ l7) * 8)]);
#pragma unroll
            for (int rt = 0; rt < 2; ++rt)
#pragma unroll
                for (int jt = 0; jt < 4; ++jt)
                    s[rt][jt] = __builtin_amdgcn_mfma_f32_16x16x32_bf16(qf[rt][ks], kf[jt], s[rt][jt], 0, 0, 0);
        }

        // p = exp2(s*kscale + bias)
#pragma unroll
        for (int rt = 0; rt < 2; ++rt)
#pragma unroll
            for (int jt = 0; jt < 4; ++jt) {
                float2 f0 = __half22float2(__builtin_bit_cast(__half2, bl[rt][jt].x));
                float2 f1 = __half22float2(__builtin_bit_cast(__half2, bl[rt][jt].y));
                float bvr[4] = {f0.x, f0.y, f1.x, f1.y};
#pragma unroll
                for (int reg = 0; reg < 4; ++reg) {
                    float p = fast_exp2(__builtin_fmaf(s[rt][jt][reg], kscale, bvr[reg]));
                    ps[(rt * 16 + quad * 4 + reg) * 72 + jt * 16 + l15] = f32_to_bf16(p);
                }
            }

        // PV + row-sum (same-wave Ps round trip; no barrier needed)
#pragma unroll
        for (int ks = 0; ks < 2; ++ks) {
            bf16x8 pf[2], vf[4];
#pragma unroll
            for (int rt = 0; rt < 2; ++rt)
                pf[rt] = *reinterpret_cast<const bf16x8*>(ps + (rt * 16 + l15) * 72 + ks * 32 + quad * 8);
#pragma unroll
            for (int nt = 0; nt < 4; ++nt)
                vf[nt] = *reinterpret_cast<const bf16x8*>(
                    &Vb[cur][(nt * 16 + l15) * 64 + (((ks * 4 + quad) ^ l7) * 8)]);
#pragma unroll
            for (int rt = 0; rt < 2; ++rt) {
#pragma unroll
                for (int nt = 0; nt < 4; ++nt)
                    o[rt][nt] = __builtin_amdgcn_mfma_f32_16x16x32_bf16(pf[rt], vf[nt], o[rt][nt], 0, 0, 0);
                lacc[rt] = __builtin_amdgcn_mfma_f32_16x16x32_bf16(pf[rt], ones, lacc[rt], 0, 0, 0);
            }
        }
    }

    // finalize
#pragma unroll
    for (int rt = 0; rt < 2; ++rt) {
        float inv[4];
#pragma unroll
        for (int reg = 0; reg < 4; ++reg) inv[reg] = 1.f / lacc[rt][reg];
#pragma unroll
        for (int nt = 0; nt < 4; ++nt)
#pragma unroll
            for (int reg = 0; reg < 4; ++reg) {
                int row = b * 1024 + i0 + rt * 16 + quad * 4 + reg;
                int col = h * 64 + nt * 16 + l15;
                aout[(size_t)row * 512 + col] = f32_to_bf16(o[rt][nt][reg] * inv[reg]);
            }
    }
}

// ---------------------------------------------------------------------------
extern "C" void kernel_launch(void* const* d_in, const int* in_sizes, int n_in,
                              void* d_out, int out_size, void* d_ws, size_t ws_size,
                              hipStream_t stream) {
    const float* x          = (const float*)d_in[0];
    const float* Hstack     = (const float*)d_in[1];
    const float* hop_logits = (const float*)d_in[2];
    const float* rel_alpha  = (const float*)d_in[3];
    const float* Wqkv       = (const float*)d_in[4];
    const float* Wproj      = (const float*)d_in[5];
    const float* bproj      = (const float*)d_in[6];
    float* out = (float*)d_out;

    char* ws = (char*)d_ws;
    unsigned short* xb    = (unsigned short*)(ws);                  // x bf16        16 MB
    unsigned short* wqb   = (unsigned short*)(ws + 16777216);       // Wqkv bf16    1.5 MB
    unsigned short* wpb   = (unsigned short*)(ws + 18350080);       // Wproj bf16   0.5 MB
    unsigned short* qkvb  = (unsigned short*)(ws + 18874368);       // qkv bf16 (Q,K used)  48 MB
    unsigned short* vtb   = (unsigned short*)(ws + 69206016);       // V^T bf16      16 MB
    unsigned short* biast = (unsigned short*)(ws + 85983232);       // bias_t fp16   16 MB
    unsigned short* aoutb = (unsigned short*)(ws + 102760448);      // attn out bf16 16 MB

    // 1. merged converts
    cvt_all<<<9216, 256, 0, stream>>>(x, Wqkv, Wproj, xb, wqb, wpb);

    // 2. fused hop-bias (all heads per block) -> fp16 tiled bias_t
    bias_fused<<<dim3(16, 16), 256, 0, stream>>>(Hstack, hop_logits, rel_alpha, (uint32_t*)biast);

    // 3. qkv GEMM (XCD-partitioned grid); V written transposed into vt
    gemm_qkv<<<1536, 256, 0, stream>>>(xb, wqb, qkvb, vtb);

    // 4. flash attention (dbuf K/V) -> [B,N,512] bf16
    flash_attn<<<dim3(8, 8, 16), 256, 0, stream>>>(qkvb, vtb, biast, aoutb);

    // 5. out = attn_out @ Wproj^T + bproj (XCD-partitioned grid) -> fp32
    gemm_proj<<<512, 256, 0, stream>>>(aoutb, wpb, out, bproj);
}